// Round 1
// baseline (1569.621 us; speedup 1.0000x reference)
//
#include <hip/hip_runtime.h>

#define TPB 256

// ---------------- CSR build ----------------

__global__ void deg_count_k(const int* __restrict__ ei, int* __restrict__ deg, int E) {
  int e = blockIdx.x * TPB + threadIdx.x;
  if (e < E) atomicAdd(&deg[ei[E + e]], 1);
}

__global__ void scan1_k(const int* __restrict__ deg, int* __restrict__ row_start,
                        int* __restrict__ chunk, float* __restrict__ invd, int n) {
  __shared__ int sh[TPB];
  int i = blockIdx.x * TPB + threadIdx.x;
  int v = (i < n) ? deg[i] : 0;
  if (i < n) invd[i] = 1.0f / fmaxf((float)v, 1.0f);
  sh[threadIdx.x] = v;
  __syncthreads();
  for (int off = 1; off < TPB; off <<= 1) {
    int t = (threadIdx.x >= off) ? sh[threadIdx.x - off] : 0;
    __syncthreads();
    sh[threadIdx.x] += t;
    __syncthreads();
  }
  if (i < n) row_start[i] = sh[threadIdx.x] - v;  // exclusive
  if (threadIdx.x == TPB - 1) chunk[blockIdx.x] = sh[TPB - 1];
}

__global__ void scan2_k(int* __restrict__ chunk, int nb) {
  __shared__ int sh[512];
  int v = (threadIdx.x < nb) ? chunk[threadIdx.x] : 0;
  sh[threadIdx.x] = v;
  __syncthreads();
  for (int off = 1; off < 512; off <<= 1) {
    int t = (threadIdx.x >= off) ? sh[threadIdx.x - off] : 0;
    __syncthreads();
    sh[threadIdx.x] += t;
    __syncthreads();
  }
  if (threadIdx.x < nb) chunk[threadIdx.x] = sh[threadIdx.x] - v;  // exclusive
}

__global__ void scan3_k(int* __restrict__ row_start, const int* __restrict__ chunk,
                        int* __restrict__ cursor, int n) {
  int i = blockIdx.x * TPB + threadIdx.x;
  if (i < n) {
    int r = row_start[i] + chunk[blockIdx.x];
    row_start[i] = r;
    cursor[i] = r;
  }
}

__global__ void fill_csr_k(const int* __restrict__ ei, int* __restrict__ cursor,
                           int* __restrict__ csr, int E) {
  int e = blockIdx.x * TPB + threadIdx.x;
  if (e >= E) return;
  int d = ei[E + e];
  int p = atomicAdd(&cursor[d], 1);
  csr[p] = ei[e];  // src
}

// ---------------- 128-dim mean aggregation (one wave per node) ----------------

__global__ void agg128_k(const float* __restrict__ h, const int* __restrict__ csr,
                         const int* __restrict__ row_start, const int* __restrict__ deg,
                         const float* __restrict__ invd, float* __restrict__ out, int n) {
  int node = (blockIdx.x << 2) + (threadIdx.x >> 6);
  if (node >= n) return;
  int lane = threadIdx.x & 63;
  int s = row_start[node];
  int c = deg[node];
  const float2* h2 = (const float2*)h;
  float ax = 0.f, ay = 0.f;
  int j = 0;
  for (; j + 1 < c; j += 2) {
    int s0 = csr[s + j];
    int s1 = csr[s + j + 1];
    float2 v0 = h2[(size_t)s0 * 64 + lane];
    float2 v1 = h2[(size_t)s1 * 64 + lane];
    ax += v0.x + v1.x;
    ay += v0.y + v1.y;
  }
  if (j < c) {
    int s0 = csr[s + j];
    float2 v0 = h2[(size_t)s0 * 64 + lane];
    ax += v0.x; ay += v0.y;
  }
  float w = invd[node];
  float2 r; r.x = ax * w; r.y = ay * w;
  ((float2*)out)[(size_t)node * 64 + lane] = r;
}

// ---------------- fused dual GEMM: out = act(Aagg@Wl^T + Ah@Wr^T + b) ----------------
// BM=64, BN=128, BK=32, 256 threads, acc 4x8 per thread.

__global__ __launch_bounds__(256) void gemm2_k(
    const float* __restrict__ Aagg, const float* __restrict__ Ah,
    const float* __restrict__ Wl, const float* __restrict__ Wr,
    const float* __restrict__ bias, float* __restrict__ out, int n, int do_relu) {
  __shared__ float As[32 * 68];   // [k][m], stride 68 (16B aligned, conflict-light)
  __shared__ float Bs[32 * 128];  // [k][o]
  int tid = threadIdx.x;
  int m0 = blockIdx.x * 64;
  int ty = tid >> 4, tx = tid & 15;  // ty: 4-row group, tx: 8-col group
  int kgA = tid & 7, mrow = tid >> 3;     // A load mapping
  int oB = tid >> 1, halfB = tid & 1;     // B load mapping

  float acc[4][8];
#pragma unroll
  for (int i = 0; i < 4; ++i)
#pragma unroll
    for (int jj = 0; jj < 8; ++jj) acc[i][jj] = 0.f;

  for (int ks = 0; ks < 8; ++ks) {
    const float* Asrc = (ks < 4) ? Aagg : Ah;
    const float* Wsrc = (ks < 4) ? Wl : Wr;
    int kb = (ks & 3) * 32;

    // global loads to regs
    float4 aR[2];
#pragma unroll
    for (int p = 0; p < 2; ++p) {
      int row = m0 + mrow + p * 32;
      if (row < n)
        aR[p] = *(const float4*)&Asrc[(size_t)row * 128 + kb + kgA * 4];
      else
        aR[p] = make_float4(0.f, 0.f, 0.f, 0.f);
    }
    float4 bR[4];
#pragma unroll
    for (int f = 0; f < 4; ++f)
      bR[f] = *(const float4*)&Wsrc[(size_t)oB * 128 + kb + halfB * 16 + f * 4];

    __syncthreads();  // prior compute done
#pragma unroll
    for (int p = 0; p < 2; ++p) {
      float* a = (float*)&aR[p];
#pragma unroll
      for (int jj = 0; jj < 4; ++jj)
        As[(kgA * 4 + jj) * 68 + mrow + p * 32] = a[jj];
    }
#pragma unroll
    for (int f = 0; f < 4; ++f) {
      float* b = (float*)&bR[f];
#pragma unroll
      for (int jj = 0; jj < 4; ++jj)
        Bs[(halfB * 16 + f * 4 + jj) * 128 + oB] = b[jj];
    }
    __syncthreads();

#pragma unroll
    for (int k = 0; k < 32; ++k) {
      float4 a4 = *(float4*)&As[k * 68 + ty * 4];
      float4 b40 = *(float4*)&Bs[k * 128 + tx * 8];
      float4 b41 = *(float4*)&Bs[k * 128 + tx * 8 + 4];
      float av[4] = {a4.x, a4.y, a4.z, a4.w};
      float bv[8] = {b40.x, b40.y, b40.z, b40.w, b41.x, b41.y, b41.z, b41.w};
#pragma unroll
      for (int i = 0; i < 4; ++i)
#pragma unroll
        for (int jj = 0; jj < 8; ++jj) acc[i][jj] += av[i] * bv[jj];
    }
  }

  float4 bb0 = *(const float4*)&bias[tx * 8];
  float4 bb1 = *(const float4*)&bias[tx * 8 + 4];
  float bbv[8] = {bb0.x, bb0.y, bb0.z, bb0.w, bb1.x, bb1.y, bb1.z, bb1.w};
#pragma unroll
  for (int i = 0; i < 4; ++i) {
    int row = m0 + ty * 4 + i;
    if (row < n) {
      float o[8];
#pragma unroll
      for (int jj = 0; jj < 8; ++jj) {
        float v = acc[i][jj] + bbv[jj];
        o[jj] = do_relu ? fmaxf(v, 0.f) : v;
      }
      *(float4*)&out[(size_t)row * 128 + tx * 8] = make_float4(o[0], o[1], o[2], o[3]);
      *(float4*)&out[(size_t)row * 128 + tx * 8 + 4] = make_float4(o[4], o[5], o[6], o[7]);
    }
  }
}

// ---------------- head weight packing: Wcat[16][128], bcat[16] ----------------

__global__ void pack_head_k(const float* __restrict__ Wal, const float* __restrict__ War,
                            const float* __restrict__ ba, const float* __restrict__ Wsl,
                            const float* __restrict__ Wsr, const float* __restrict__ bsx,
                            const float* __restrict__ Wel, const float* __restrict__ Wer,
                            const float* __restrict__ be, float* __restrict__ Wcat,
                            float* __restrict__ bcat) {
  int t = blockIdx.x * TPB + threadIdx.x;
  if (t < 384) Wcat[t] = Wal[t];
  else if (t < 640) Wcat[t] = Wsl[t - 384];
  else if (t < 1024) Wcat[t] = Wel[t - 640];
  else if (t < 1408) Wcat[t] = War[t - 1024];
  else if (t < 1664) Wcat[t] = Wsr[t - 1408];
  else if (t < 2048) Wcat[t] = Wer[t - 1664];
  if (t < 16) {
    float b = 0.f;
    if (t >= 8 && t < 11) b = ba[t - 8];
    else if (t >= 11 && t < 13) b = bsx[t - 11];
    else if (t >= 13) b = be[t - 13];
    bcat[t] = b;
  }
}

// ---------------- head GEMM: out_lr[n,16] = h3 @ Wcat^T + bcat ----------------

__global__ __launch_bounds__(256) void head_gemm_k(const float* __restrict__ h,
                                                   const float* __restrict__ Wcat,
                                                   const float* __restrict__ bcat,
                                                   float* __restrict__ out_lr, int n) {
  __shared__ float hs[64 * 132];
  __shared__ float Ws[16 * 128];
  __shared__ float bsh[16];
  int tid = threadIdx.x;
  int m0 = blockIdx.x * 64;
  // load weights
  {
    float4 w0 = *(const float4*)&Wcat[tid * 8];
    float4 w1 = *(const float4*)&Wcat[tid * 8 + 4];
    *(float4*)&Ws[tid * 8] = w0;
    *(float4*)&Ws[tid * 8 + 4] = w1;
    if (tid < 16) bsh[tid] = bcat[tid];
  }
  // load 64 rows of h
  {
    int row = tid >> 2, q = tid & 3;
    int grow = m0 + row;
#pragma unroll
    for (int j = 0; j < 8; ++j) {
      float4 v = (grow < n) ? *(const float4*)&h[(size_t)grow * 128 + q * 32 + j * 4]
                            : make_float4(0.f, 0.f, 0.f, 0.f);
      *(float4*)&hs[row * 132 + q * 32 + j * 4] = v;
    }
  }
  __syncthreads();
  int row = tid & 63, og = tid >> 6;
  float acc[4] = {0.f, 0.f, 0.f, 0.f};
#pragma unroll
  for (int k4 = 0; k4 < 32; ++k4) {
    float4 hv = *(float4*)&hs[row * 132 + k4 * 4];
#pragma unroll
    for (int i = 0; i < 4; ++i) {
      float4 wv = *(float4*)&Ws[(og * 4 + i) * 128 + k4 * 4];
      acc[i] += hv.x * wv.x + hv.y * wv.y + hv.z * wv.z + hv.w * wv.w;
    }
  }
  int grow = m0 + row;
  if (grow < n) {
#pragma unroll
    for (int i = 0; i < 4; ++i)
      out_lr[(size_t)grow * 16 + og * 4 + i] = acc[i] + bsh[og * 4 + i];
  }
}

// ---------------- 8-dim aggregation + output write ----------------
// out layout: age [n,3] @0, sex [n,2] @3n, eth [n,3] @5n

__global__ void agg8_k(const float* __restrict__ hlr, const int* __restrict__ csr,
                       const int* __restrict__ row_start, const int* __restrict__ deg,
                       const float* __restrict__ invd, float* __restrict__ out, int n) {
  int node = (blockIdx.x << 2) + (threadIdx.x >> 6);
  if (node >= n) return;
  int lane = threadIdx.x & 63;
  int c = lane & 7, g = lane >> 3;
  int s = row_start[node], cnt = deg[node];
  float acc = 0.f;
  for (int j = g; j < cnt; j += 8) {
    int src = csr[s + j];
    acc += hlr[(size_t)src * 16 + c];
  }
  acc += __shfl_xor(acc, 8);
  acc += __shfl_xor(acc, 16);
  acc += __shfl_xor(acc, 32);
  if (g == 0) {
    float r = acc * invd[node] + hlr[(size_t)node * 16 + 8 + c];
    if (c < 3) out[(size_t)node * 3 + c] = r;
    else if (c < 5) out[(size_t)3 * n + (size_t)node * 2 + (c - 3)] = r;
    else out[(size_t)5 * n + (size_t)node * 3 + (c - 5)] = r;
  }
}

// ---------------- launch ----------------

extern "C" void kernel_launch(void* const* d_in, const int* in_sizes, int n_in,
                              void* d_out, int out_size, void* d_ws, size_t ws_size,
                              hipStream_t stream) {
  const float* x = (const float*)d_in[0];
  const int* ei = (const int*)d_in[1];
  const float* W1l = (const float*)d_in[2];
  const float* W1r = (const float*)d_in[3];
  const float* b1 = (const float*)d_in[4];
  const float* W2l = (const float*)d_in[5];
  const float* W2r = (const float*)d_in[6];
  const float* b2 = (const float*)d_in[7];
  const float* W3l = (const float*)d_in[8];
  const float* W3r = (const float*)d_in[9];
  const float* b3 = (const float*)d_in[10];
  const float* Wal = (const float*)d_in[11];
  const float* War = (const float*)d_in[12];
  const float* ba = (const float*)d_in[13];
  const float* Wsl = (const float*)d_in[14];
  const float* Wsr = (const float*)d_in[15];
  const float* bsx = (const float*)d_in[16];
  const float* Wel = (const float*)d_in[17];
  const float* Wer = (const float*)d_in[18];
  const float* be = (const float*)d_in[19];

  int N = in_sizes[0] / 128;
  int E = in_sizes[1] / 2;

  char* w = (char*)d_ws;
  auto alloc = [&](size_t b) {
    char* p = w;
    w += (b + 255) & ~(size_t)255;
    return p;
  };
  int* deg = (int*)alloc((size_t)N * 4);
  int* row_start = (int*)alloc((size_t)N * 4);
  int* cursor = (int*)alloc((size_t)N * 4);
  int* chunk = (int*)alloc(512 * 4);
  float* invd = (float*)alloc((size_t)N * 4);
  int* csr = (int*)alloc((size_t)E * 4);
  float* aggbuf = (float*)alloc((size_t)N * 128 * 4);
  float* h_a = (float*)alloc((size_t)N * 128 * 4);
  float* h_b = (float*)alloc((size_t)N * 128 * 4);
  float* head_lr = (float*)alloc((size_t)N * 16 * 4);
  float* Wcat = (float*)alloc(16 * 128 * 4);
  float* bcat = (float*)alloc(16 * 4);

  int nbN = (N + TPB - 1) / TPB;
  int nbE = (E + TPB - 1) / TPB;
  int nbNode = (N + 3) / 4;
  int nbM = (N + 63) / 64;

  hipMemsetAsync(deg, 0, (size_t)N * 4, stream);
  deg_count_k<<<nbE, TPB, 0, stream>>>(ei, deg, E);
  scan1_k<<<nbN, TPB, 0, stream>>>(deg, row_start, chunk, invd, N);
  scan2_k<<<1, 512, 0, stream>>>(chunk, nbN);
  scan3_k<<<nbN, TPB, 0, stream>>>(row_start, chunk, cursor, N);
  fill_csr_k<<<nbE, TPB, 0, stream>>>(ei, cursor, csr, E);

  // layer 1: x -> h_a
  agg128_k<<<nbNode, TPB, 0, stream>>>(x, csr, row_start, deg, invd, aggbuf, N);
  gemm2_k<<<nbM, TPB, 0, stream>>>(aggbuf, x, W1l, W1r, b1, h_a, N, 1);
  // layer 2: h_a -> h_b
  agg128_k<<<nbNode, TPB, 0, stream>>>(h_a, csr, row_start, deg, invd, aggbuf, N);
  gemm2_k<<<nbM, TPB, 0, stream>>>(aggbuf, h_a, W2l, W2r, b2, h_b, N, 1);
  // layer 3: h_b -> h_a
  agg128_k<<<nbNode, TPB, 0, stream>>>(h_b, csr, row_start, deg, invd, aggbuf, N);
  gemm2_k<<<nbM, TPB, 0, stream>>>(aggbuf, h_b, W3l, W3r, b3, h_a, N, 1);
  // heads: transform first (8 dims), then aggregate 8-dim
  pack_head_k<<<8, TPB, 0, stream>>>(Wal, War, ba, Wsl, Wsr, bsx, Wel, Wer, be, Wcat, bcat);
  head_gemm_k<<<nbM, TPB, 0, stream>>>(h_a, Wcat, bcat, head_lr, N);
  agg8_k<<<nbNode, TPB, 0, stream>>>(head_lr, csr, row_start, deg, invd, (float*)d_out, N);
}